// Round 3
// baseline (88.525 us; speedup 1.0000x reference)
//
#include <hip/hip_runtime.h>
#include <hip/hip_bf16.h>

// Forward warp (bilinear splatting): binning w/ duplicate-push + payload precompute
// + per-tile LDS accumulation.
//   img  [B=8, C=3, H=180, W=320] f32
//   flow [B=8, 2,  H=180, W=320] f32
//   scale=4 -> out [B, C, 720, 1280] f32

#define B_ 8
#define C_ 3
#define H_ 180
#define W_ 320
#define HW_ (H_ * W_)
#define SCALE_ 4
#define Ho_ (H_ * SCALE_)          // 720
#define Wo_ (W_ * SCALE_)          // 1280
#define TH_ 40
#define TW_ 64
#define NTY_ (Ho_ / TH_)           // 18
#define NTX_ (Wo_ / TW_)           // 20
#define NTILES_ (B_ * NTY_ * NTX_) // 2880
#define NPIX_ (B_ * H_ * W_)       // 460800 (= 1800 * 256 exactly)
#define TILE_ELEMS_ (C_ * TH_ * TW_) // 7680 floats = 30 KB

// ---------------- pass A: payload precompute + per-bin counts ----------------
__global__ __launch_bounds__(256) void prep_kernel(const float* __restrict__ img,
                                                   const float* __restrict__ flow,
                                                   unsigned* __restrict__ counts,
                                                   unsigned short* __restrict__ binpack,
                                                   float2* __restrict__ pxy,
                                                   float4* __restrict__ pv) {
    int idx = blockIdx.x * 256 + threadIdx.x;   // grid exactly NPIX_/256
    int w = idx % W_;
    int t = idx / W_;
    int h = t % H_;
    int b = t / H_;
    int hw = h * W_ + w;

    float fx = flow[(b * 2 + 0) * HW_ + hw];
    float fy = flow[(b * 2 + 1) * HW_ + hw];
    float x = ((float)w + fx) * (float)SCALE_;
    float y = ((float)h + fy) * (float)SCALE_;
    int ix0 = (int)floorf(x);
    int iy0 = (int)floorf(y);
    int xlo = max(ix0, 0), xhi = min(ix0 + 1, Wo_ - 1);
    int ylo = max(iy0, 0), yhi = min(iy0 + 1, Ho_ - 1);
    bool valid = (xlo <= xhi) && (ylo <= yhi);

    int txlo = xlo >> 6;           // TW_=64
    int txhi = xhi >> 6;
    int tylo = ylo / TH_;
    int tyhi = yhi / TH_;
    bool xc = valid && (txhi > txlo);
    bool yc = valid && (tyhi > tylo);

    unsigned short bp = 0;
    if (valid)
        bp = (unsigned short)(txlo | (tylo << 5) | (xc ? (1u << 10) : 0u) |
                              (yc ? (1u << 11) : 0u) | (1u << 12));
    binpack[idx] = bp;
    pxy[idx] = make_float2(x, y);
    const float* imgb = img + (size_t)b * C_ * HW_;
    pv[idx] = make_float4(imgb[hw], imgb[HW_ + hw], imgb[2 * HW_ + hw], 0.0f);

    int lane = threadIdx.x & 63;
    #pragma unroll
    for (int j = 0; j < 4; ++j) {
        int dx = j & 1, dy = j >> 1;
        bool act = valid && (dx == 0 || xc) && (dy == 0 || yc);
        int key = act ? ((b * NTY_ + tylo + dy) * NTX_ + txlo + dx) : -1;
        unsigned long long todo = __ballot(act);
        while (todo) {
            int leader = __ffsll((long long)todo) - 1;
            int kl = __shfl(key, leader);
            unsigned long long mem = __ballot(act && key == kl);
            if (act && key == kl &&
                __popcll(mem & ((1ull << lane) - 1ull)) == 0)
                atomicAdd(&counts[kl], (unsigned)__popcll(mem));
            todo &= ~mem;
        }
    }
}

// ---------------- pass B: exclusive scan of counts -> offs, cursor ----------------
#define SCAN_PER_T 12   // 256*12 = 3072 >= 2880
__global__ __launch_bounds__(256) void scan_kernel(const unsigned* __restrict__ counts,
                                                   unsigned* __restrict__ offs,
                                                   unsigned* __restrict__ cursor) {
    __shared__ unsigned part[256];
    int tid = threadIdx.x;
    unsigned local[SCAN_PER_T];
    unsigned sum = 0;
    for (int i = 0; i < SCAN_PER_T; ++i) {
        int j = tid * SCAN_PER_T + i;
        unsigned c = (j < NTILES_) ? counts[j] : 0u;
        local[i] = sum;
        sum += c;
    }
    part[tid] = sum;
    __syncthreads();
    for (int off = 1; off < 256; off <<= 1) {
        unsigned v = (tid >= off) ? part[tid - off] : 0u;
        __syncthreads();
        part[tid] += v;
        __syncthreads();
    }
    unsigned base = (tid > 0) ? part[tid - 1] : 0u;
    for (int i = 0; i < SCAN_PER_T; ++i) {
        int j = tid * SCAN_PER_T + i;
        if (j < NTILES_) {
            unsigned o = base + local[i];
            offs[j] = o;
            cursor[j] = o;
        }
    }
}

// ---------------- pass C: duplicate-push pixel indices into bins ----------------
__global__ __launch_bounds__(256) void push_kernel(const unsigned short* __restrict__ binpack,
                                                   unsigned* __restrict__ cursor,
                                                   unsigned* __restrict__ idxrec) {
    int idx = blockIdx.x * 256 + threadIdx.x;
    unsigned bp = binpack[idx];
    bool valid = (bp >> 12) & 1;
    int txlo = bp & 31;
    int tylo = (bp >> 5) & 31;
    bool xc = (bp >> 10) & 1;
    bool yc = (bp >> 11) & 1;
    int b = idx / HW_;

    int lane = threadIdx.x & 63;
    #pragma unroll
    for (int j = 0; j < 4; ++j) {
        int dx = j & 1, dy = j >> 1;
        bool act = valid && (dx == 0 || xc) && (dy == 0 || yc);
        int key = act ? ((b * NTY_ + tylo + dy) * NTX_ + txlo + dx) : -1;
        unsigned long long todo = __ballot(act);
        while (todo) {
            int leader = __ffsll((long long)todo) - 1;
            int kl = __shfl(key, leader);
            unsigned long long mem = __ballot(act && key == kl);
            if (act && key == kl) {
                int rank = __popcll(mem & ((1ull << lane) - 1ull));
                unsigned base = 0;
                if (rank == 0)
                    base = atomicAdd(&cursor[kl], (unsigned)__popcll(mem));
                base = __shfl(base, leader);
                idxrec[base + rank] = (unsigned)idx;
            }
            todo &= ~mem;
        }
    }
}

// ---------------- pass D: per-tile LDS accumulate + coalesced write ----------------
__global__ __launch_bounds__(256) void accum_kernel(const unsigned* __restrict__ counts,
                                                    const unsigned* __restrict__ offs,
                                                    const unsigned* __restrict__ idxrec,
                                                    const float2* __restrict__ pxy,
                                                    const float4* __restrict__ pv,
                                                    float* __restrict__ out) {
    __shared__ __align__(16) float acc[TILE_ELEMS_];
    int tile = blockIdx.x;
    int tx = tile % NTX_;
    int tt = tile / NTX_;
    int ty = tt % NTY_;
    int b  = tt / NTY_;
    int px0 = tx * TW_;
    int py0 = ty * TH_;

    #pragma unroll
    for (int i = threadIdx.x; i < TILE_ELEMS_ / 4; i += 256)
        *reinterpret_cast<float4*>(&acc[i * 4]) = make_float4(0.f, 0.f, 0.f, 0.f);
    __syncthreads();

    unsigned start = offs[tile];
    unsigned cnt   = counts[tile];
    for (unsigned r = start + threadIdx.x; r < start + cnt; r += 256) {
        unsigned pidx = idxrec[r];
        float2 xy = pxy[pidx];
        float4 v  = pv[pidx];
        float x0f = floorf(xy.x), y0f = floorf(xy.y);
        int ix0 = (int)x0f, iy0 = (int)y0f;
        float ax = xy.x - x0f, ay = xy.y - y0f;
        float wx[2] = {1.0f - ax, ax};
        float wy[2] = {1.0f - ay, ay};
        #pragma unroll
        for (int ky = 0; ky < 2; ++ky) {
            int yi = iy0 + ky;
            if (yi < py0 || yi >= py0 + TH_) continue;   // in-tile => in-image
            #pragma unroll
            for (int kx = 0; kx < 2; ++kx) {
                int xi = ix0 + kx;
                if (xi < px0 || xi >= px0 + TW_) continue;
                float wt = wx[kx] * wy[ky];
                int la = (yi - py0) * TW_ + (xi - px0);
                atomicAdd(&acc[0 * TH_ * TW_ + la], v.x * wt);
                atomicAdd(&acc[1 * TH_ * TW_ + la], v.y * wt);
                atomicAdd(&acc[2 * TH_ * TW_ + la], v.z * wt);
            }
        }
    }
    __syncthreads();

    const size_t outb = (size_t)b * C_ * Ho_ * Wo_;
    for (int j = threadIdx.x; j < TILE_ELEMS_ / 4; j += 256) {
        int f = j * 4;
        int c = f / (TH_ * TW_);
        int rem = f - c * (TH_ * TW_);
        int yy = rem / TW_;
        int xx = rem - yy * TW_;
        float4 v = *reinterpret_cast<const float4*>(&acc[f]);
        *reinterpret_cast<float4*>(
            &out[outb + (size_t)c * Ho_ * Wo_ + (size_t)(py0 + yy) * Wo_ + (px0 + xx)]) = v;
    }
}

// ---------------- fallback: naive global-atomic splat ----------------
__global__ __launch_bounds__(256) void splat_naive(const float* __restrict__ img,
                                                   const float* __restrict__ flow,
                                                   const int* __restrict__ scale_p,
                                                   float* __restrict__ out) {
    int idx = blockIdx.x * blockDim.x + threadIdx.x;
    if (idx >= NPIX_) return;
    const int s = *scale_p;
    const int Ho = H_ * s, Wo = W_ * s;
    int w = idx % W_;
    int t = idx / W_;
    int h = t % H_;
    int b = t / H_;
    const int hw = h * W_ + w;
    float fx = flow[((b * 2 + 0) * H_) * W_ + hw];
    float fy = flow[((b * 2 + 1) * H_) * W_ + hw];
    float x = ((float)w + fx) * (float)s;
    float y = ((float)h + fy) * (float)s;
    float x0f = floorf(x), y0f = floorf(y);
    float ax = x - x0f, ay = y - y0f;
    int ix0 = (int)x0f, iy0 = (int)y0f;
    const size_t img_b = (size_t)b * C_ * HW_;
    float v0 = img[img_b + 0 * (size_t)HW_ + hw];
    float v1 = img[img_b + 1 * (size_t)HW_ + hw];
    float v2 = img[img_b + 2 * (size_t)HW_ + hw];
    const size_t out_b = (size_t)b * C_ * Ho * Wo;
    const size_t out_chs = (size_t)Ho * Wo;
    float wx[2] = {1.0f - ax, ax};
    float wy[2] = {1.0f - ay, ay};
    #pragma unroll
    for (int ky = 0; ky < 2; ++ky) {
        int yi = iy0 + ky;
        if (yi < 0 || yi > Ho - 1) continue;
        #pragma unroll
        for (int kx = 0; kx < 2; ++kx) {
            int xi = ix0 + kx;
            if (xi < 0 || xi > Wo - 1) continue;
            float wt = wx[kx] * wy[ky];
            size_t base = out_b + (size_t)yi * Wo + (size_t)xi;
            atomicAdd(&out[base + 0 * out_chs], v0 * wt);
            atomicAdd(&out[base + 1 * out_chs], v1 * wt);
            atomicAdd(&out[base + 2 * out_chs], v2 * wt);
        }
    }
}

extern "C" void kernel_launch(void* const* d_in, const int* in_sizes, int n_in,
                              void* d_out, int out_size, void* d_ws, size_t ws_size,
                              hipStream_t stream) {
    const float* img   = (const float*)d_in[0];
    const float* flow  = (const float*)d_in[1];
    const int*   scale = (const int*)d_in[2];
    float* out = (float*)d_out;

    // ws layout (all 16B-aligned):
    //   counts u32[2880] | offs u32[2880] | cursor u32[2880] |
    //   binpack u16[NPIX] | pxy float2[NPIX] | pv float4[NPIX] | idxrec u32[4*NPIX]
    const size_t tbl       = (size_t)NTILES_ * sizeof(unsigned);      // 11520
    const size_t off_offs    = tbl;                                   // 11520
    const size_t off_cursor  = 2 * tbl;                               // 23040
    const size_t off_binpack = 3 * tbl;                               // 34560
    const size_t off_pxy     = off_binpack + (size_t)NPIX_ * 2;       // 956160
    const size_t off_pv      = off_pxy + (size_t)NPIX_ * 8;           // 4642560
    const size_t off_idxrec  = off_pv + (size_t)NPIX_ * 16;           // 12015360
    const size_t need        = off_idxrec + (size_t)4 * NPIX_ * 4;    // 19388160

    const bool scale4 = (out_size == B_ * C_ * Ho_ * Wo_);

    if (scale4 && ws_size >= need) {
        char* ws = (char*)d_ws;
        unsigned*       counts  = (unsigned*)(ws);
        unsigned*       offs    = (unsigned*)(ws + off_offs);
        unsigned*       cursor  = (unsigned*)(ws + off_cursor);
        unsigned short* binpack = (unsigned short*)(ws + off_binpack);
        float2*         pxy     = (float2*)(ws + off_pxy);
        float4*         pv      = (float4*)(ws + off_pv);
        unsigned*       idxrec  = (unsigned*)(ws + off_idxrec);

        hipMemsetAsync(counts, 0, tbl, stream);
        prep_kernel<<<NPIX_ / 256, 256, 0, stream>>>(img, flow, counts, binpack, pxy, pv);
        scan_kernel<<<1, 256, 0, stream>>>(counts, offs, cursor);
        push_kernel<<<NPIX_ / 256, 256, 0, stream>>>(binpack, cursor, idxrec);
        accum_kernel<<<NTILES_, 256, 0, stream>>>(counts, offs, idxrec, pxy, pv, out);
    } else {
        hipMemsetAsync(out, 0, (size_t)out_size * sizeof(float), stream);
        splat_naive<<<(NPIX_ + 255) / 256, 256, 0, stream>>>(img, flow, scale, out);
    }
}

// Round 4
// 46.115 us; speedup vs baseline: 1.9196x; 1.9196x over previous
//
#include <hip/hip_runtime.h>
#include <hip/hip_bf16.h>

// Forward warp (bilinear splatting), direct per-tile gather-from-window.
//   img  [B=8, C=3, H=180, W=320] f32
//   flow [B=8, 2,  H=180, W=320] f32
//   scale=4 -> out [B, C, 720, 1280] f32
//
// Each output tile (40x64) gathers from a fixed 36x42 input window (valid when
// |flow| <= 12; margin has 1-px slack each side). Pixels with |flow| > 12 are
// excluded from the tile pass by the *same* predicate and splatted with global
// atomics in a second kernel (expected ~zero such pixels for N(0,2) flow, but
// exact for any input). Output is written with exclusive tile stores -> no
// memset, no workspace, no multi-pass binning.

#define B_ 8
#define C_ 3
#define H_ 180
#define W_ 320
#define HW_ (H_ * W_)
#define SCALE_ 4
#define Ho_ (H_ * SCALE_)            // 720
#define Wo_ (W_ * SCALE_)            // 1280
#define TH_ 40
#define TW_ 64
#define NTY_ (Ho_ / TH_)             // 18
#define NTX_ (Wo_ / TW_)             // 20
#define NTILES_ (B_ * NTY_ * NTX_)   // 2880
#define NPIX_ (B_ * H_ * W_)         // 460800 (= 1800 * 256)
#define TILE_ELEMS_ (C_ * TH_ * TW_) // 7680 floats = 30 KB

#define MARGIN_ 12.0f
#define WIN_H_ 36                    // TH/4 + 2*12 + 2
#define WIN_W_ 42                    // TW/4 + 2*12 + 2

__global__ __launch_bounds__(256) void warp_tile_kernel(const float* __restrict__ img,
                                                        const float* __restrict__ flow,
                                                        float* __restrict__ out) {
    __shared__ __align__(16) float acc[TILE_ELEMS_];
    const int tile = blockIdx.x;
    const int tx = tile % NTX_;
    const int tt = tile / NTX_;
    const int ty = tt % NTY_;
    const int b  = tt / NTY_;
    const int px0 = tx * TW_;
    const int py0 = ty * TH_;

    #pragma unroll
    for (int i = threadIdx.x * 4; i < TILE_ELEMS_; i += 1024)
        *reinterpret_cast<float4*>(&acc[i]) = make_float4(0.f, 0.f, 0.f, 0.f);
    __syncthreads();

    const float* __restrict__ fxp  = flow + (size_t)(b * 2 + 0) * HW_;
    const float* __restrict__ fyp  = flow + (size_t)(b * 2 + 1) * HW_;
    const float* __restrict__ imgb = img + (size_t)b * C_ * HW_;

    const int hb = py0 >> 2;   // py0/4
    const int wb = px0 >> 2;   // px0/4

    for (int i = threadIdx.x; i < WIN_H_ * WIN_W_; i += 256) {
        int r = i / WIN_W_;
        int c = i - r * WIN_W_;
        int h = hb - 13 + r;
        int w = wb - 13 + c;
        if ((unsigned)h >= (unsigned)H_ || (unsigned)w >= (unsigned)W_) continue;
        int hw = h * W_ + w;
        float fx = fxp[hw];
        float fy = fyp[hw];
        // Must be the EXACT complement of outlier_kernel's predicate.
        if (!(fabsf(fx) <= MARGIN_ && fabsf(fy) <= MARGIN_)) continue;

        float x = ((float)w + fx) * (float)SCALE_;
        float y = ((float)h + fy) * (float)SCALE_;
        float x0f = floorf(x), y0f = floorf(y);
        int ix0 = (int)x0f - px0;   // tile-local
        int iy0 = (int)y0f - py0;
        bool cx[2] = {(unsigned)ix0 < (unsigned)TW_, (unsigned)(ix0 + 1) < (unsigned)TW_};
        bool cy[2] = {(unsigned)iy0 < (unsigned)TH_, (unsigned)(iy0 + 1) < (unsigned)TH_};
        if (!((cx[0] | cx[1]) & (cy[0] | cy[1]))) continue;

        float ax = x - x0f, ay = y - y0f;
        float v0 = imgb[hw];
        float v1 = imgb[HW_ + hw];
        float v2 = imgb[2 * HW_ + hw];
        float wxs[2] = {1.0f - ax, ax};
        float wys[2] = {1.0f - ay, ay};
        #pragma unroll
        for (int ky = 0; ky < 2; ++ky) {
            if (!cy[ky]) continue;
            #pragma unroll
            for (int kx = 0; kx < 2; ++kx) {
                if (!cx[kx]) continue;
                float wt = wxs[kx] * wys[ky];
                int la = (iy0 + ky) * TW_ + (ix0 + kx);
                atomicAdd(&acc[0 * TH_ * TW_ + la], v0 * wt);
                atomicAdd(&acc[1 * TH_ * TW_ + la], v1 * wt);
                atomicAdd(&acc[2 * TH_ * TW_ + la], v2 * wt);
            }
        }
    }
    __syncthreads();

    // exclusive coalesced float4 write-out (overwrites poison -> no memset needed)
    const size_t outb = (size_t)b * C_ * Ho_ * Wo_;
    for (int j = threadIdx.x; j < TILE_ELEMS_ / 4; j += 256) {
        int f = j * 4;
        int ch = f / (TH_ * TW_);
        int rem = f - ch * (TH_ * TW_);
        int yy = rem / TW_;
        int xx = rem - yy * TW_;
        *reinterpret_cast<float4*>(
            &out[outb + (size_t)ch * Ho_ * Wo_ + (size_t)(py0 + yy) * Wo_ + (px0 + xx)]) =
            *reinterpret_cast<const float4*>(&acc[f]);
    }
}

// Pixels with |flow| > MARGIN_: exact global-atomic splat (runs AFTER tile writes).
__global__ __launch_bounds__(256) void outlier_kernel(const float* __restrict__ img,
                                                      const float* __restrict__ flow,
                                                      float* __restrict__ out) {
    int idx = blockIdx.x * 256 + threadIdx.x;   // grid exactly NPIX_/256
    int w = idx % W_;
    int t = idx / W_;
    int h = t % H_;
    int b = t / H_;
    int hw = h * W_ + w;
    float fx = flow[(b * 2 + 0) * HW_ + hw];
    float fy = flow[(b * 2 + 1) * HW_ + hw];
    if (fabsf(fx) <= MARGIN_ && fabsf(fy) <= MARGIN_) return;   // handled by tile pass

    float x = ((float)w + fx) * (float)SCALE_;
    float y = ((float)h + fy) * (float)SCALE_;
    float x0f = floorf(x), y0f = floorf(y);
    float ax = x - x0f, ay = y - y0f;
    int ix0 = (int)x0f, iy0 = (int)y0f;
    const float* imgb = img + (size_t)b * C_ * HW_;
    float v0 = imgb[hw];
    float v1 = imgb[HW_ + hw];
    float v2 = imgb[2 * HW_ + hw];
    const size_t out_b = (size_t)b * C_ * Ho_ * Wo_;
    const size_t chs = (size_t)Ho_ * Wo_;
    float wxs[2] = {1.0f - ax, ax};
    float wys[2] = {1.0f - ay, ay};
    #pragma unroll
    for (int ky = 0; ky < 2; ++ky) {
        int yi = iy0 + ky;
        if ((unsigned)yi >= (unsigned)Ho_) continue;
        #pragma unroll
        for (int kx = 0; kx < 2; ++kx) {
            int xi = ix0 + kx;
            if ((unsigned)xi >= (unsigned)Wo_) continue;
            float wt = wxs[kx] * wys[ky];
            size_t base = out_b + (size_t)yi * Wo_ + (size_t)xi;
            atomicAdd(&out[base + 0 * chs], v0 * wt);
            atomicAdd(&out[base + 1 * chs], v1 * wt);
            atomicAdd(&out[base + 2 * chs], v2 * wt);
        }
    }
}

// ---------------- fallback: naive global-atomic splat (scale != 4) ----------------
__global__ __launch_bounds__(256) void splat_naive(const float* __restrict__ img,
                                                   const float* __restrict__ flow,
                                                   const int* __restrict__ scale_p,
                                                   float* __restrict__ out) {
    int idx = blockIdx.x * blockDim.x + threadIdx.x;
    if (idx >= NPIX_) return;
    const int s = *scale_p;
    const int Ho = H_ * s, Wo = W_ * s;
    int w = idx % W_;
    int t = idx / W_;
    int h = t % H_;
    int b = t / H_;
    const int hw = h * W_ + w;
    float fx = flow[((b * 2 + 0) * H_) * W_ + hw];
    float fy = flow[((b * 2 + 1) * H_) * W_ + hw];
    float x = ((float)w + fx) * (float)s;
    float y = ((float)h + fy) * (float)s;
    float x0f = floorf(x), y0f = floorf(y);
    float ax = x - x0f, ay = y - y0f;
    int ix0 = (int)x0f, iy0 = (int)y0f;
    const size_t img_b = (size_t)b * C_ * HW_;
    float v0 = img[img_b + 0 * (size_t)HW_ + hw];
    float v1 = img[img_b + 1 * (size_t)HW_ + hw];
    float v2 = img[img_b + 2 * (size_t)HW_ + hw];
    const size_t out_b = (size_t)b * C_ * Ho * Wo;
    const size_t out_chs = (size_t)Ho * Wo;
    float wxs[2] = {1.0f - ax, ax};
    float wys[2] = {1.0f - ay, ay};
    #pragma unroll
    for (int ky = 0; ky < 2; ++ky) {
        int yi = iy0 + ky;
        if (yi < 0 || yi > Ho - 1) continue;
        #pragma unroll
        for (int kx = 0; kx < 2; ++kx) {
            int xi = ix0 + kx;
            if (xi < 0 || xi > Wo - 1) continue;
            float wt = wxs[kx] * wys[ky];
            size_t base = out_b + (size_t)yi * Wo + (size_t)xi;
            atomicAdd(&out[base + 0 * out_chs], v0 * wt);
            atomicAdd(&out[base + 1 * out_chs], v1 * wt);
            atomicAdd(&out[base + 2 * out_chs], v2 * wt);
        }
    }
}

extern "C" void kernel_launch(void* const* d_in, const int* in_sizes, int n_in,
                              void* d_out, int out_size, void* d_ws, size_t ws_size,
                              hipStream_t stream) {
    const float* img   = (const float*)d_in[0];
    const float* flow  = (const float*)d_in[1];
    const int*   scale = (const int*)d_in[2];
    float* out = (float*)d_out;

    const bool scale4 = (out_size == B_ * C_ * Ho_ * Wo_);

    if (scale4) {
        // Tile pass overwrites the whole output (exclusive stores), then the
        // outlier pass atomically adds the (rare) |flow|>12 pixels on top.
        warp_tile_kernel<<<NTILES_, 256, 0, stream>>>(img, flow, out);
        outlier_kernel<<<NPIX_ / 256, 256, 0, stream>>>(img, flow, out);
    } else {
        hipMemsetAsync(out, 0, (size_t)out_size * sizeof(float), stream);
        splat_naive<<<(NPIX_ + 255) / 256, 256, 0, stream>>>(img, flow, scale, out);
    }
}